// Round 5
// baseline (319.722 us; speedup 1.0000x reference)
//
#include <hip/hip_runtime.h>
#include <math.h>

// Problem constants
#define DM   512
#define NH   8
#define HD   64
#define B_   2
#define L_   1024
#define M_   (B_ * L_)   // 2048 rows

typedef __attribute__((ext_vector_type(8))) short  bfrag;   // 8 bf16 (4 VGPRs, 16 B)
typedef __attribute__((ext_vector_type(4))) float  fv4;     // MFMA acc
typedef __attribute__((ext_vector_type(4))) unsigned short usv4;  // 8 B
typedef __attribute__((ext_vector_type(8))) unsigned short usv8;  // 16 B

__device__ __forceinline__ unsigned short f32_bf16_rne(float f) {
    unsigned u = __float_as_uint(f);
    unsigned r = u + 0x7FFF + ((u >> 16) & 1);
    return (unsigned short)(r >> 16);
}
__device__ __forceinline__ float bf16_f32(unsigned short h) {
    return __uint_as_float(((unsigned)h) << 16);
}

// async global->LDS, 16 B per lane. LDS dest = wave-uniform base + lane*16.
__device__ __forceinline__ void stage16(const unsigned short* g, unsigned short* l) {
    __builtin_amdgcn_global_load_lds(
        (const __attribute__((address_space(1))) void*)g,
        (__attribute__((address_space(3))) void*)l,
        16, 0, 0);
}

// ---------------- device-scope grid barrier (sense/generation) ------------------
// bar[0] = arrival counter, bar[1] = generation. Zeroed by hipMemsetAsync before
// launch. Safe because all GRID_N=256 blocks are co-resident: launch_bounds(256,2)
// caps VGPR<=256 (>=2 blocks/CU) and LDS 34.8KB allows 4/CU -> capacity >= 512.
#define GRID_N 256

__device__ __forceinline__ void grid_barrier(unsigned* bar) {
    __syncthreads();
    if (threadIdx.x == 0) {
        __threadfence();   // release: drain stores, write back L2 (agent scope)
        unsigned g = __hip_atomic_load(bar + 1, __ATOMIC_RELAXED, __HIP_MEMORY_SCOPE_AGENT);
        unsigned a = __hip_atomic_fetch_add(bar, 1u, __ATOMIC_ACQ_REL, __HIP_MEMORY_SCOPE_AGENT);
        if (a == GRID_N - 1) {
            __hip_atomic_store(bar, 0u, __ATOMIC_RELAXED, __HIP_MEMORY_SCOPE_AGENT);
            __hip_atomic_store(bar + 1, g + 1u, __ATOMIC_RELEASE, __HIP_MEMORY_SCOPE_AGENT);
        } else {
            while (__hip_atomic_load(bar + 1, __ATOMIC_ACQUIRE, __HIP_MEMORY_SCOPE_AGENT) == g)
                __builtin_amdgcn_s_sleep(2);
        }
        __threadfence();   // acquire: invalidate L1/L2 so fresh data is read
    }
    __syncthreads();
}

// ---------------- split-bf16 MFMA GEMM phase (round-3 verified structure) -------
// C-tile 64x64, 4 waves, wave w owns m-frag w; double-buffered stage-ahead,
// one barrier per k-step. LDS carved from the shared arena:
//   Ah = S+0, Al = S+4096, Bh = S+8192, Bl = S+12288  (each [2][2048] shorts)
#define TM 64
#define TN 64
#define TK 32
#define LDA 32
#define NSTEP (DM / TK)   // 16

__device__ __forceinline__ void mfma_gemm_bf16(
    unsigned short* S,
    const unsigned short* __restrict__ Ahg, const unsigned short* __restrict__ Alg,
    const unsigned short* __restrict__ Bhg, const unsigned short* __restrict__ Blg,
    const float* __restrict__ bias, float* __restrict__ C, int do_exp,
    int m0, int n0) {
    unsigned short* Ah = S;
    unsigned short* Al = S + 4096;
    unsigned short* Bh = S + 8192;
    unsigned short* Bl = S + 12288;

    const int tid  = threadIdx.x;
    const int wave = tid >> 6, lane = tid & 63;
    const int quad = lane >> 4, r16 = lane & 15;

    const int srow = lane >> 2;
    const int scol = (lane & 3) << 3;
    const size_t gaBase = (size_t)(m0 + wave * 16 + srow) * DM + scol;
    const size_t gbBase = (size_t)(n0 + wave * 16 + srow) * DM + scol;
    const int ldst = wave * 512;   // chunk offset in shorts (16 rows x 32)

    fv4 acc[4] = {};

    stage16(Ahg + gaBase, Ah + ldst);
    stage16(Alg + gaBase, Al + ldst);
    stage16(Bhg + gbBase, Bh + ldst);
    stage16(Blg + gbBase, Bl + ldst);
    __syncthreads();

    int cur = 0;
    for (int t = 0; t < NSTEP; ++t) {
        if (t + 1 < NSTEP) {       // stage-ahead: issue before compute, drain after
            const size_t koff = (size_t)(t + 1) * TK;
            const int d = (cur ^ 1) * 2048 + ldst;
            stage16(Ahg + gaBase + koff, Ah + d);
            stage16(Alg + gaBase + koff, Al + d);
            stage16(Bhg + gbBase + koff, Bh + d);
            stage16(Blg + gbBase + koff, Bl + d);
        }
        const int base = cur * 2048;
        const int aoff = base + (wave * 16 + r16) * LDA + quad * 8;
        bfrag ah = *(const bfrag*)(Ah + aoff);
        bfrag al = *(const bfrag*)(Al + aoff);
        bfrag bh[4], bl[4];
#pragma unroll
        for (int j = 0; j < 4; ++j) {
            const int boff = base + (j * 16 + r16) * LDA + quad * 8;
            bh[j] = *(const bfrag*)(Bh + boff);
            bl[j] = *(const bfrag*)(Bl + boff);
        }
#pragma unroll
        for (int j = 0; j < 4; ++j) {
            acc[j] = __builtin_amdgcn_mfma_f32_16x16x32_bf16(ah, bh[j], acc[j], 0, 0, 0);
            acc[j] = __builtin_amdgcn_mfma_f32_16x16x32_bf16(ah, bl[j], acc[j], 0, 0, 0);
            acc[j] = __builtin_amdgcn_mfma_f32_16x16x32_bf16(al, bh[j], acc[j], 0, 0, 0);
        }
        __syncthreads();
        cur ^= 1;
    }

    // epilogue: D[row = quad*4 + r][col = r16]
#pragma unroll
    for (int j = 0; j < 4; ++j) {
        int n = n0 + j * 16 + r16;
        float bn = bias[n];
#pragma unroll
        for (int r = 0; r < 4; ++r) {
            int m = m0 + wave * 16 + quad * 4 + r;
            float v = acc[j][r] + bn;
            if (do_exp) v = __expf(v);
            C[(size_t)m * DM + n] = v;
        }
    }
}

// ---------------- fused persistent kernel: 5 phases, 4 software grid barriers ---
#define JT 64

__global__ __launch_bounds__(256, 2) void fused_kernel(
    const float* __restrict__ x,
    const float* __restrict__ Wq, const float* __restrict__ bq,
    const float* __restrict__ Wk, const float* __restrict__ bk,
    const float* __restrict__ Wv, const float* __restrict__ bv,
    const float* __restrict__ Wo, const float* __restrict__ bo,
    float* __restrict__ out, float* __restrict__ ws) {
    __shared__ __align__(16) unsigned char SMEM[34816];

    // workspace carve (must match kernel_launch)
    const size_t NQ = (size_t)M_ * DM;               // 1,048,576
    float* Qe    = ws;
    float* Ke    = ws + NQ;
    float* V     = ws + 2 * NQ;
    float* Spart = ws + 3 * NQ;                       // 16*16*4096 floats
    float* zred  = ws + 4 * NQ;                       // 1024 floats (atomic target)
    unsigned short* u = (unsigned short*)(ws + 4 * NQ + 1024);
    unsigned short* xh  = u;
    unsigned short* xl  = u + NQ;
    unsigned short* wh  = u + 2 * NQ;                 // 3 x 262144
    unsigned short* wl  = u + 2 * NQ + 786432;
    unsigned short* jh  = u + 2 * NQ + 2 * 786432;
    unsigned short* jl  = jh + NQ;
    unsigned short* w2h = jl + NQ;                    // 2 x 262144
    unsigned short* w2l = w2h + 524288;
    unsigned* bar = (unsigned*)(w2l + 524288);        // 2 uints, memset to 0

    const int id  = blockIdx.x;
    const int tid = threadIdx.x;

    // ---- phase 1: prep (1793 chunk-units over 256 blocks) ----
    for (int c = id; c < 1793; c += GRID_N) {
        if (c >= 1792) {   // zero the z accumulator (1024 floats)
            float4 zv = {0.f, 0.f, 0.f, 0.f};
            *(float4*)(zred + (size_t)tid * 4) = zv;
            continue;
        }
        const float* src; unsigned short *dh, *dl; size_t off;
        if (c < 1024) {
            src = x; dh = xh; dl = xl; off = (size_t)c * 1024;
        } else {
            int wsel = (c - 1024) >> 8;               // 0..2
            int wb   = (c - 1024) & 255;
            src = (wsel == 0) ? Wq : (wsel == 1) ? Wk : Wv;
            dh = wh + (size_t)wsel * 262144;
            dl = wl + (size_t)wsel * 262144;
            off = (size_t)wb * 1024;
        }
        size_t i = off + (size_t)tid * 4;
        float4 v = *(const float4*)(src + i);
        usv4 h, l;
        h.x = f32_bf16_rne(v.x); l.x = f32_bf16_rne(v.x - bf16_f32(h.x));
        h.y = f32_bf16_rne(v.y); l.y = f32_bf16_rne(v.y - bf16_f32(h.y));
        h.z = f32_bf16_rne(v.z); l.z = f32_bf16_rne(v.z - bf16_f32(h.z));
        h.w = f32_bf16_rne(v.w); l.w = f32_bf16_rne(v.w - bf16_f32(h.w));
        *(usv4*)(dh + i) = h;
        *(usv4*)(dl + i) = l;
    }
    grid_barrier(bar);

    // ---- phase 2: QKV GEMM — each block does its (m,n) tile for z=0,1,2 ----
    {
        const int m0 = (id >> 3) * TM;                // 0..31 -> rows
        const int n0 = (id & 7) * TN;                 // 0..7  -> cols
#pragma unroll 1
        for (int z = 0; z < 3; ++z) {
            const float* bb = (z == 0) ? bq : (z == 1) ? bk : bv;
            float* C = (z == 0) ? Qe : (z == 1) ? Ke : V;
            mfma_gemm_bf16((unsigned short*)SMEM, xh, xl,
                           wh + (size_t)z * 262144, wl + (size_t)z * 262144,
                           bb, C, z < 2, m0, n0);
        }
    }
    grid_barrier(bar);

    // ---- phase 3: KV stats (256 blocks: split = id&15, bh = id>>4) ----
    {
        float* EK = (float*)SMEM;                     // [JT][HD+4]
        float* VS = EK + JT * (HD + 4);
        const int split = id & 15, bh = id >> 4;
        const int b = bh >> 3, h = bh & 7;
        const int j0 = split * JT;
#pragma unroll
        for (int t = 0; t < 4; ++t) {
            int idx = tid + t * 256;
            int r = idx >> 4;
            int c = (idx & 15) << 2;
            size_t row = (size_t)(b * L_ + j0 + r) * DM + h * HD + c;
            *(float4*)&EK[r * (HD + 4) + c] = *(const float4*)(Ke + row);
            *(float4*)&VS[r * (HD + 4) + c] = *(const float4*)(V + row);
        }
        __syncthreads();

        const int tx = tid & 15, ty = tid >> 4;
        float acc[4][4] = {{0.f}};
#pragma unroll 8
        for (int jj = 0; jj < JT; ++jj) {
            float4 ek = *(const float4*)&EK[jj * (HD + 4) + ty * 4];
            float4 vs = *(const float4*)&VS[jj * (HD + 4) + tx * 4];
            float e[4] = {ek.x, ek.y, ek.z, ek.w};
            float v[4] = {vs.x, vs.y, vs.z, vs.w};
#pragma unroll
            for (int i = 0; i < 4; ++i)
#pragma unroll
                for (int j = 0; j < 4; ++j) acc[i][j] += e[i] * v[j];
        }

        float* sp = Spart + ((size_t)bh * 16 + split) * (HD * HD);
#pragma unroll
        for (int i = 0; i < 4; ++i) {
            float4 o; o.x = acc[i][0]; o.y = acc[i][1]; o.z = acc[i][2]; o.w = acc[i][3];
            *(float4*)(sp + (ty * 4 + i) * HD + tx * 4) = o;
        }
        if (tid < HD) {
            float z = 0.f;
#pragma unroll 8
            for (int jj = 0; jj < JT; ++jj) z += EK[jj * (HD + 4) + tid];
            atomicAdd(zred + (size_t)bh * HD + tid, z);
        }
    }
    grid_barrier(bar);

    // ---- phase 4: mid (128 W2-fold blocks + 64 scaled_eq blocks, 64 idle) ----
    if (id < 128) {
        float* Sl  = (float*)SMEM;                    // [HD][HD+4]
        float* Wol = Sl + HD * (HD + 4);
        const int b = id >> 6, r = id & 63;
        const int h = r >> 3, nq = r & 7;
        const int n0 = nq * 64, bh = b * NH + h;
        const float* sp = Spart + (size_t)bh * 16 * (HD * HD);
#pragma unroll
        for (int t4 = 0; t4 < 4; ++t4) {
            int idx4 = tid + t4 * 256;                // 0..1023 (float4 index)
            const float* p0 = sp + (size_t)idx4 * 4;
            float4 s = {0.f, 0.f, 0.f, 0.f};
#pragma unroll
            for (int p = 0; p < 16; ++p) {
                float4 v = *(const float4*)(p0 + (size_t)p * (HD * HD));
                s.x += v.x; s.y += v.y; s.z += v.z; s.w += v.w;
            }
            int d = idx4 >> 4, e4 = (idx4 & 15) << 2;
            *(float4*)&Sl[d * (HD + 4) + e4] = s;
            *(float4*)&Wol[d * (HD + 4) + e4] =
                *(const float4*)(Wo + (size_t)(n0 + d) * DM + h * HD + e4);
        }
        __syncthreads();
        const int nl = tid & 15;
        const int d0 = tid >> 4;
        float acc[4][4] = {};
#pragma unroll
        for (int e4 = 0; e4 < 16; ++e4) {
            float4 w[4], s[4];
#pragma unroll
            for (int j = 0; j < 4; ++j)
                w[j] = *(const float4*)&Wol[(nl + j * 16) * (HD + 4) + e4 * 4];
#pragma unroll
            for (int i = 0; i < 4; ++i)
                s[i] = *(const float4*)&Sl[(d0 + i * 16) * (HD + 4) + e4 * 4];
#pragma unroll
            for (int j = 0; j < 4; ++j)
#pragma unroll
                for (int i = 0; i < 4; ++i)
                    acc[j][i] += w[j].x * s[i].x + w[j].y * s[i].y
                               + w[j].z * s[i].z + w[j].w * s[i].w;
        }
#pragma unroll
        for (int j = 0; j < 4; ++j) {
            int n = n0 + nl + j * 16;
#pragma unroll
            for (int i = 0; i < 4; ++i) {
                int d = d0 + i * 16;
                size_t addr = ((size_t)(b * DM + n)) * DM + h * HD + d;
                float v = acc[j][i];
                unsigned short hh = f32_bf16_rne(v);
                w2h[addr] = hh;
                w2l[addr] = f32_bf16_rne(v - bf16_f32(hh));
            }
        }
    } else if (id < 192) {
        const int bid2 = id - 128;           // 0..63, 32 rows each
        const int w = tid >> 6, lane = tid & 63;
        const int b = bid2 >> 5;
        const int row0 = bid2 * 32 + w * 8;  // wave handles 8 rows
        const float4 z0 = *(const float4*)(zred + (size_t)b * DM + lane * 8);
        const float4 z1 = *(const float4*)(zred + (size_t)b * DM + lane * 8 + 4);
#pragma unroll
        for (int rr = 0; rr < 8; ++rr) {
            const size_t rowoff = (size_t)(row0 + rr) * DM + lane * 8;
            float4 q0 = *(const float4*)(Qe + rowoff);
            float4 q1 = *(const float4*)(Qe + rowoff + 4);
            float part = q0.x * z0.x + q0.y * z0.y + q0.z * z0.z + q0.w * z0.w
                       + q1.x * z1.x + q1.y * z1.y + q1.z * z1.z + q1.w * z1.w;
            part += __shfl_xor(part, 1, 64);
            part += __shfl_xor(part, 2, 64);
            part += __shfl_xor(part, 4, 64);
            float inv = 1.0f / part;
            float v[8] = {q0.x * inv, q0.y * inv, q0.z * inv, q0.w * inv,
                          q1.x * inv, q1.y * inv, q1.z * inv, q1.w * inv};
            usv8 hv, lv;
#pragma unroll
            for (int k = 0; k < 8; ++k) {
                unsigned short hh = f32_bf16_rne(v[k]);
                hv[k] = hh;
                lv[k] = f32_bf16_rne(v[k] - bf16_f32(hh));
            }
            *(usv8*)(jh + rowoff) = hv;
            *(usv8*)(jl + rowoff) = lv;
        }
    }
    grid_barrier(bar);

    // ---- phase 5: out GEMM (256 blocks, one 64x64 tile each) ----
    {
        const int by = id >> 3;                       // 0..31
        const int b  = by >> 4;                       // batch
        const int m0 = by * TM;
        const int n0 = (id & 7) * TN;
        mfma_gemm_bf16((unsigned short*)SMEM, jh, jl,
                       w2h + (size_t)b * 262144, w2l + (size_t)b * 262144,
                       bo, out, 0, m0, n0);
    }
}

// ---------------- launch ----------------
extern "C" void kernel_launch(void* const* d_in, const int* in_sizes, int n_in,
                              void* d_out, int out_size, void* d_ws, size_t ws_size,
                              hipStream_t stream) {
    const float* x  = (const float*)d_in[0];
    const float* Wq = (const float*)d_in[1];
    const float* bq = (const float*)d_in[2];
    const float* Wk = (const float*)d_in[3];
    const float* bk = (const float*)d_in[4];
    const float* Wv = (const float*)d_in[5];
    const float* bv = (const float*)d_in[6];
    const float* Wo = (const float*)d_in[7];
    const float* bo = (const float*)d_in[8];
    float* out = (float*)d_out;
    float* ws  = (float*)d_ws;

    // barrier location (must match kernel carve): after w2l
    const size_t NQ = (size_t)M_ * DM;
    unsigned short* u = (unsigned short*)(ws + 4 * NQ + 1024);
    unsigned* bar = (unsigned*)(u + 2 * NQ + 2 * 786432 + 2 * NQ + 2 * 524288);
    hipMemsetAsync((void*)bar, 0, 8, stream);   // cnt = gen = 0 (capture-safe)

    fused_kernel<<<dim3(GRID_N), dim3(256), 0, stream>>>(
        x, Wq, bq, Wk, bk, Wv, bv, Wo, bo, out, ws);
}

// Round 6
// 130.197 us; speedup vs baseline: 2.4557x; 2.4557x over previous
//
#include <hip/hip_runtime.h>
#include <math.h>

// Problem constants
#define DM   512
#define NH   8
#define HD   64
#define B_   2
#define L_   1024
#define M_   (B_ * L_)   // 2048 rows

typedef __attribute__((ext_vector_type(8))) short  bfrag;   // 8 bf16 (4 VGPRs, 16 B)
typedef __attribute__((ext_vector_type(4))) float  fv4;     // MFMA acc
typedef __attribute__((ext_vector_type(4))) unsigned short usv4;  // 8 B
typedef __attribute__((ext_vector_type(8))) unsigned short usv8;  // 16 B

__device__ __forceinline__ unsigned short f32_bf16_rne(float f) {
    unsigned u = __float_as_uint(f);
    unsigned r = u + 0x7FFF + ((u >> 16) & 1);
    return (unsigned short)(r >> 16);
}
__device__ __forceinline__ float bf16_f32(unsigned short h) {
    return __uint_as_float(((unsigned)h) << 16);
}

// 8 f32 -> 8 bf16 hi + 8 bf16 lo (Markidis split), packed for one ds_write_b128
__device__ __forceinline__ void cvt8(const float4 a, const float4 b,
                                     usv8* hi, usv8* lo) {
    float f[8] = {a.x, a.y, a.z, a.w, b.x, b.y, b.z, b.w};
#pragma unroll
    for (int k = 0; k < 8; ++k) {
        unsigned short h = f32_bf16_rne(f[k]);
        (*hi)[k] = h;
        (*lo)[k] = f32_bf16_rne(f[k] - bf16_f32(h));
    }
}

// async global->LDS, 16 B per lane. LDS dest = wave-uniform base + lane*16.
__device__ __forceinline__ void stage16(const unsigned short* g, unsigned short* l) {
    __builtin_amdgcn_global_load_lds(
        (const __attribute__((address_space(1))) void*)g,
        (__attribute__((address_space(3))) void*)l,
        16, 0, 0);
}

// ---------------- GEMM geometry (round-3 verified) ------------------------------
// C-tile 64x64, 256 threads = 4 waves; wave w owns m-frag w (rows w*16..+15),
// 4 n-frags, Markidis 3-pass per frag, double-buffered, 1 barrier per k-step.
#define TM 64
#define TN 64
#define TK 32
#define LDA 32
#define NSTEP (DM / TK)   // 16

// ---------------- QKV GEMM with fused f32->hi/lo conversion (prep deleted) ------
// A = x (f32), B = Wq/Wk/Wv (f32). Reg-stage next k-tile (T14: load early),
// convert+ds_write into back buffer after MFMA, one barrier per step.
// Block (0,0,0) also zeroes zred (read by kv_stats, next kernel -> ordered).
__global__ __launch_bounds__(256) void gemm_qkv_kernel(
    const float* __restrict__ x,
    const float* __restrict__ Wq, const float* __restrict__ Wk,
    const float* __restrict__ Wv,
    const float* __restrict__ bq, const float* __restrict__ bk,
    const float* __restrict__ bv,
    float* __restrict__ Qe, float* __restrict__ Ke, float* __restrict__ V,
    float* __restrict__ zred) {
    __shared__ __align__(16) unsigned short Ah[2][TM * LDA];
    __shared__ __align__(16) unsigned short Al[2][TM * LDA];
    __shared__ __align__(16) unsigned short Bh[2][TN * LDA];
    __shared__ __align__(16) unsigned short Bl[2][TN * LDA];

    const int z = blockIdx.z;
    const float* W    = (z == 0) ? Wq : (z == 1) ? Wk : Wv;
    const float* bias = (z == 0) ? bq : (z == 1) ? bk : bv;
    float* C          = (z == 0) ? Qe : (z == 1) ? Ke : V;
    const int m0 = blockIdx.y * TM, n0 = blockIdx.x * TN;
    const int do_exp = (z < 2);

    const int tid = threadIdx.x;
    if (blockIdx.x == 0 && blockIdx.y == 0 && z == 0) {
        float4 zv = {0.f, 0.f, 0.f, 0.f};
        *(float4*)(zred + (size_t)tid * 4) = zv;   // 1024 floats
    }

    const int wave = tid >> 6, lane = tid & 63;
    const int quad = lane >> 4, r16 = lane & 15;
    // staging: wave w covers 16 rows of A and of B; lane -> row lane>>2,
    // cols (lane&3)*8 .. +7 (8 f32 = 2 float4 -> 16 bf16 hi + 16 lo? no: 8+8)
    const int srow = lane >> 2;
    const int scol = (lane & 3) << 3;
    const size_t gaBase = (size_t)(m0 + wave * 16 + srow) * DM + scol;
    const size_t gbBase = (size_t)(n0 + wave * 16 + srow) * DM + scol;
    const int soff = (wave * 16 + srow) * LDA + scol;   // LDS short offset

    fv4 acc[4] = {};

    // prologue: k-tile 0 -> buf 0
    {
        float4 a0 = *(const float4*)(x + gaBase);
        float4 a1 = *(const float4*)(x + gaBase + 4);
        float4 b0 = *(const float4*)(W + gbBase);
        float4 b1 = *(const float4*)(W + gbBase + 4);
        usv8 h, l;
        cvt8(a0, a1, &h, &l);
        *(usv8*)(&Ah[0][soff]) = h; *(usv8*)(&Al[0][soff]) = l;
        cvt8(b0, b1, &h, &l);
        *(usv8*)(&Bh[0][soff]) = h; *(usv8*)(&Bl[0][soff]) = l;
    }
    __syncthreads();

    int cur = 0;
    for (int t = 0; t < NSTEP; ++t) {
        // T14 load-early: issue next tile's global loads before the MFMA phase
        float4 na0, na1, nb0, nb1;
        if (t + 1 < NSTEP) {
            const size_t k = (size_t)(t + 1) * TK;
            na0 = *(const float4*)(x + gaBase + k);
            na1 = *(const float4*)(x + gaBase + k + 4);
            nb0 = *(const float4*)(W + gbBase + k);
            nb1 = *(const float4*)(W + gbBase + k + 4);
        }
        const int aoff = (wave * 16 + r16) * LDA + quad * 8;
        bfrag ah = *(const bfrag*)(&Ah[cur][aoff]);
        bfrag al = *(const bfrag*)(&Al[cur][aoff]);
        bfrag bh[4], bl[4];
#pragma unroll
        for (int j = 0; j < 4; ++j) {
            const int boff = (j * 16 + r16) * LDA + quad * 8;
            bh[j] = *(const bfrag*)(&Bh[cur][boff]);
            bl[j] = *(const bfrag*)(&Bl[cur][boff]);
        }
#pragma unroll
        for (int j = 0; j < 4; ++j) {
            acc[j] = __builtin_amdgcn_mfma_f32_16x16x32_bf16(ah, bh[j], acc[j], 0, 0, 0);
            acc[j] = __builtin_amdgcn_mfma_f32_16x16x32_bf16(ah, bl[j], acc[j], 0, 0, 0);
            acc[j] = __builtin_amdgcn_mfma_f32_16x16x32_bf16(al, bh[j], acc[j], 0, 0, 0);
        }
        // write-late: convert + store into back buffer (loads have had MFMA
        // phase to land); barrier separates from next step's reads.
        if (t + 1 < NSTEP) {
            usv8 h, l;
            cvt8(na0, na1, &h, &l);
            *(usv8*)(&Ah[cur ^ 1][soff]) = h; *(usv8*)(&Al[cur ^ 1][soff]) = l;
            cvt8(nb0, nb1, &h, &l);
            *(usv8*)(&Bh[cur ^ 1][soff]) = h; *(usv8*)(&Bl[cur ^ 1][soff]) = l;
        }
        __syncthreads();
        cur ^= 1;
    }

    // epilogue: D[row = quad*4 + r][col = r16]
#pragma unroll
    for (int j = 0; j < 4; ++j) {
        int n = n0 + j * 16 + r16;
        float bn = bias[n];
#pragma unroll
        for (int r = 0; r < 4; ++r) {
            int m = m0 + wave * 16 + quad * 4 + r;
            float v = acc[j][r] + bn;
            if (do_exp) v = __expf(v);
            C[(size_t)m * DM + n] = v;
        }
    }
}

// ---------------- out GEMM: bf16 hi/lo inputs via global_load_lds (r3 body) -----
__global__ __launch_bounds__(256) void gemm_out_kernel(
    const unsigned short* __restrict__ jh, const unsigned short* __restrict__ jl,
    const unsigned short* __restrict__ w2h, const unsigned short* __restrict__ w2l,
    const float* __restrict__ bo, float* __restrict__ C) {
    __shared__ __align__(16) unsigned short Ah[2][TM * LDA];
    __shared__ __align__(16) unsigned short Al[2][TM * LDA];
    __shared__ __align__(16) unsigned short Bh[2][TN * LDA];
    __shared__ __align__(16) unsigned short Bl[2][TN * LDA];

    const int bb = blockIdx.y >> 4;   // TM=64: rows 0..1023 -> b=0, else b=1
    const unsigned short* Ahg = jh;
    const unsigned short* Alg = jl;
    const unsigned short* Bhg = w2h + (size_t)bb * 262144;
    const unsigned short* Blg = w2l + (size_t)bb * 262144;
    const int m0 = blockIdx.y * TM, n0 = blockIdx.x * TN;

    const int tid  = threadIdx.x;
    const int wave = tid >> 6, lane = tid & 63;
    const int quad = lane >> 4, r16 = lane & 15;
    const int srow = lane >> 2;
    const int scol = (lane & 3) << 3;
    const size_t gaBase = (size_t)(m0 + wave * 16 + srow) * DM + scol;
    const size_t gbBase = (size_t)(n0 + wave * 16 + srow) * DM + scol;
    const int ldst = wave * 512;

    fv4 acc[4] = {};

    stage16(Ahg + gaBase, &Ah[0][ldst]);
    stage16(Alg + gaBase, &Al[0][ldst]);
    stage16(Bhg + gbBase, &Bh[0][ldst]);
    stage16(Blg + gbBase, &Bl[0][ldst]);
    __syncthreads();

    int cur = 0;
    for (int t = 0; t < NSTEP; ++t) {
        if (t + 1 < NSTEP) {
            const size_t koff = (size_t)(t + 1) * TK;
            stage16(Ahg + gaBase + koff, &Ah[cur ^ 1][ldst]);
            stage16(Alg + gaBase + koff, &Al[cur ^ 1][ldst]);
            stage16(Bhg + gbBase + koff, &Bh[cur ^ 1][ldst]);
            stage16(Blg + gbBase + koff, &Bl[cur ^ 1][ldst]);
        }
        const int aoff = (wave * 16 + r16) * LDA + quad * 8;
        bfrag ah = *(const bfrag*)(&Ah[cur][aoff]);
        bfrag al = *(const bfrag*)(&Al[cur][aoff]);
        bfrag bh[4], bl[4];
#pragma unroll
        for (int j = 0; j < 4; ++j) {
            const int boff = (j * 16 + r16) * LDA + quad * 8;
            bh[j] = *(const bfrag*)(&Bh[cur][boff]);
            bl[j] = *(const bfrag*)(&Bl[cur][boff]);
        }
#pragma unroll
        for (int j = 0; j < 4; ++j) {
            acc[j] = __builtin_amdgcn_mfma_f32_16x16x32_bf16(ah, bh[j], acc[j], 0, 0, 0);
            acc[j] = __builtin_amdgcn_mfma_f32_16x16x32_bf16(ah, bl[j], acc[j], 0, 0, 0);
            acc[j] = __builtin_amdgcn_mfma_f32_16x16x32_bf16(al, bh[j], acc[j], 0, 0, 0);
        }
        __syncthreads();
        cur ^= 1;
    }

#pragma unroll
    for (int j = 0; j < 4; ++j) {
        int n = n0 + j * 16 + r16;
        float bn = bo[n];
#pragma unroll
        for (int r = 0; r < 4; ++r) {
            int m = m0 + wave * 16 + quad * 4 + r;
            C[(size_t)m * DM + n] = acc[j][r] + bn;
        }
    }
}

// ---------------- KV stats: partial S[d,e] per (bh, split); z via atomicAdd ------
#define JT 64
__global__ __launch_bounds__(256) void kv_stats_kernel(
    const float* __restrict__ Kbuf, const float* __restrict__ Vbuf,
    float* __restrict__ Spart, float* __restrict__ zred) {
    const int split = blockIdx.x, bh = blockIdx.y;
    const int b = bh >> 3, h = bh & 7;
    const int j0 = split * JT;

    __shared__ __align__(16) float EK[JT][HD + 4];
    __shared__ __align__(16) float VS[JT][HD + 4];

    const int tid = threadIdx.x;
#pragma unroll
    for (int t = 0; t < 4; ++t) {
        int idx = tid + t * 256;
        int r = idx >> 4;
        int c = (idx & 15) << 2;
        size_t row = (size_t)(b * L_ + j0 + r) * DM + h * HD + c;
        *(float4*)&EK[r][c] = *(const float4*)(Kbuf + row);
        *(float4*)&VS[r][c] = *(const float4*)(Vbuf + row);
    }
    __syncthreads();

    const int tx = tid & 15, ty = tid >> 4;
    float acc[4][4] = {{0.f}};
#pragma unroll 8
    for (int jj = 0; jj < JT; ++jj) {
        float4 ek = *(const float4*)&EK[jj][ty * 4];
        float4 vs = *(const float4*)&VS[jj][tx * 4];
        float e[4] = {ek.x, ek.y, ek.z, ek.w};
        float v[4] = {vs.x, vs.y, vs.z, vs.w};
#pragma unroll
        for (int i = 0; i < 4; ++i)
#pragma unroll
            for (int j = 0; j < 4; ++j) acc[i][j] += e[i] * v[j];
    }

    float* sp = Spart + ((size_t)bh * 16 + split) * (HD * HD);
#pragma unroll
    for (int i = 0; i < 4; ++i) {
        float4 o; o.x = acc[i][0]; o.y = acc[i][1]; o.z = acc[i][2]; o.w = acc[i][3];
        *(float4*)(sp + (ty * 4 + i) * HD + tx * 4) = o;
    }
    if (tid < HD) {
        float z = 0.f;
#pragma unroll 8
        for (int jj = 0; jj < JT; ++jj) z += EK[jj][tid];
        atomicAdd(zred + (size_t)bh * HD + tid, z);   // zred[b*512 + h*64 + d]
    }
}

// ---------------- mid: W2 fold + scaled_eq --------------------------------------
// Blocks 0..127:  W2_b[n][h*64+d] = sum_e Wo[n][h*64+e] * S_bh[d][e]  (bf16 hi/lo)
// Blocks 128..191: scaled_eq[i][c] = expQ[i][c] / denom(i, head(c)) -> jh/jl
__global__ __launch_bounds__(256) void mid_kernel(
    const float* __restrict__ Spart, const float* __restrict__ zred,
    const float* __restrict__ Qbuf, const float* __restrict__ Wo,
    unsigned short* __restrict__ w2h, unsigned short* __restrict__ w2l,
    unsigned short* __restrict__ jh, unsigned short* __restrict__ jl) {
    const int tid = threadIdx.x;
    const int bid = blockIdx.x;
    if (bid < 128) {
        __shared__ __align__(16) float Sl[HD][HD + 4];
        __shared__ __align__(16) float Wol[HD][HD + 4];
        const int b = bid >> 6, r = bid & 63;
        const int h = r >> 3, nq = r & 7;
        const int n0 = nq * 64, bh = b * NH + h;
        const float* sp = Spart + (size_t)bh * 16 * (HD * HD);
#pragma unroll
        for (int t4 = 0; t4 < 4; ++t4) {
            int idx4 = tid + t4 * 256;               // 0..1023 (float4 index)
            const float* p0 = sp + (size_t)idx4 * 4;
            float4 s = {0.f, 0.f, 0.f, 0.f};
#pragma unroll
            for (int p = 0; p < 16; ++p) {
                float4 v = *(const float4*)(p0 + (size_t)p * (HD * HD));
                s.x += v.x; s.y += v.y; s.z += v.z; s.w += v.w;
            }
            int d = idx4 >> 4, e4 = (idx4 & 15) << 2;
            *(float4*)&Sl[d][e4] = s;
            *(float4*)&Wol[d][e4] =
                *(const float4*)(Wo + (size_t)(n0 + d) * DM + h * HD + e4);
        }
        __syncthreads();
        const int nl = tid & 15;
        const int d0 = tid >> 4;
        float acc[4][4] = {};
#pragma unroll
        for (int e4 = 0; e4 < 16; ++e4) {
            float4 w[4], s[4];
#pragma unroll
            for (int j = 0; j < 4; ++j) w[j] = *(const float4*)&Wol[nl + j * 16][e4 * 4];
#pragma unroll
            for (int i = 0; i < 4; ++i) s[i] = *(const float4*)&Sl[d0 + i * 16][e4 * 4];
#pragma unroll
            for (int j = 0; j < 4; ++j)
#pragma unroll
                for (int i = 0; i < 4; ++i)
                    acc[j][i] += w[j].x * s[i].x + w[j].y * s[i].y
                               + w[j].z * s[i].z + w[j].w * s[i].w;
        }
#pragma unroll
        for (int j = 0; j < 4; ++j) {
            int n = n0 + nl + j * 16;
#pragma unroll
            for (int i = 0; i < 4; ++i) {
                int d = d0 + i * 16;
                size_t addr = ((size_t)(b * DM + n)) * DM + h * HD + d;
                float v = acc[j][i];
                unsigned short hh = f32_bf16_rne(v);
                w2h[addr] = hh;
                w2l[addr] = f32_bf16_rne(v - bf16_f32(hh));
            }
        }
    } else {
        const int bid2 = bid - 128;          // 0..63, 32 rows each
        const int w = tid >> 6, lane = tid & 63;
        const int b = bid2 >> 5;
        const int row0 = bid2 * 32 + w * 8;  // wave handles 8 rows
        const float4 z0 = *(const float4*)(zred + (size_t)b * DM + lane * 8);
        const float4 z1 = *(const float4*)(zred + (size_t)b * DM + lane * 8 + 4);
#pragma unroll
        for (int rr = 0; rr < 8; ++rr) {
            const size_t rowoff = (size_t)(row0 + rr) * DM + lane * 8;
            float4 q0 = *(const float4*)(Qbuf + rowoff);
            float4 q1 = *(const float4*)(Qbuf + rowoff + 4);
            float part = q0.x * z0.x + q0.y * z0.y + q0.z * z0.z + q0.w * z0.w
                       + q1.x * z1.x + q1.y * z1.y + q1.z * z1.z + q1.w * z1.w;
            part += __shfl_xor(part, 1, 64);
            part += __shfl_xor(part, 2, 64);
            part += __shfl_xor(part, 4, 64);
            float inv = 1.0f / part;
            float v[8] = {q0.x * inv, q0.y * inv, q0.z * inv, q0.w * inv,
                          q1.x * inv, q1.y * inv, q1.z * inv, q1.w * inv};
            usv8 hv, lv;
#pragma unroll
            for (int k = 0; k < 8; ++k) {
                unsigned short hh = f32_bf16_rne(v[k]);
                hv[k] = hh;
                lv[k] = f32_bf16_rne(v[k] - bf16_f32(hh));
            }
            *(usv8*)(jh + rowoff) = hv;
            *(usv8*)(jl + rowoff) = lv;
        }
    }
}

// ---------------- launch: 4 kernels (prep deleted) ------------------------------
extern "C" void kernel_launch(void* const* d_in, const int* in_sizes, int n_in,
                              void* d_out, int out_size, void* d_ws, size_t ws_size,
                              hipStream_t stream) {
    const float* x  = (const float*)d_in[0];
    const float* Wq = (const float*)d_in[1];
    const float* bq = (const float*)d_in[2];
    const float* Wk = (const float*)d_in[3];
    const float* bk = (const float*)d_in[4];
    const float* Wv = (const float*)d_in[5];
    const float* bv = (const float*)d_in[6];
    const float* Wo = (const float*)d_in[7];
    const float* bo = (const float*)d_in[8];
    float* out = (float*)d_out;

    float* f = (float*)d_ws;
    const size_t NQ = (size_t)M_ * DM;               // 1,048,576
    float* Qe    = f;
    float* Ke    = f + NQ;
    float* V     = f + 2 * NQ;
    float* Spart = f + 3 * NQ;                        // 16*16*4096 floats
    float* zred  = f + 4 * NQ;                        // 1024 floats (atomic target)
    unsigned short* u = (unsigned short*)(f + 4 * NQ + 1024);
    unsigned short* jh  = u;
    unsigned short* jl  = jh + NQ;
    unsigned short* w2h = jl + NQ;                    // 2 x 262144
    unsigned short* w2l = w2h + 524288;

    dim3 gQKV(DM / TN, M_ / TM, 3);   // (8, 32, 3) = 768 blocks = 3/CU
    gemm_qkv_kernel<<<gQKV, 256, 0, stream>>>(x, Wq, Wk, Wv, bq, bk, bv,
                                              Qe, Ke, V, zred);

    kv_stats_kernel<<<dim3(16, 16), 256, 0, stream>>>(Ke, V, Spart, zred);

    mid_kernel<<<192, 256, 0, stream>>>(Spart, zred, Qe, Wo, w2h, w2l, jh, jl);

    dim3 gO(DM / TN, M_ / TM, 1);     // (8, 32) = 256 blocks
    gemm_out_kernel<<<gO, 256, 0, stream>>>(jh, jl, w2h, w2l, bo, out);
}